// Round 6
// baseline (213.269 us; speedup 1.0000x reference)
//
#include <hip/hip_runtime.h>
#include <hip/hip_fp16.h>
#include <math.h>

#define N_NODES 100000
#define N_EDGES 1600000
#define F_DIM 64
#define BSH 8                              // 256 nodes per bucket
#define NBUCK ((N_NODES + 255) >> 8)       // 391
#define CAP 8192                           // slots/bucket (avg 4096, sigma ~64)
#define EPT 16
#define TILE (256 * EPT)                   // 4096 edges per pass1 block

// ---------------- init bucket cursors ----------------
__global__ __launch_bounds__(256) void init_k(int* __restrict__ bcur) {
    int i = blockIdx.x * 256 + threadIdx.x;
    if (i < NBUCK) bcur[i] = i * CAP;
}

// ---------------- pass1: single-pass bucket scatter (fixed-capacity) ----------------
__global__ __launch_bounds__(256) void pass1_k(const int* __restrict__ src,
                                               const int* __restrict__ dst,
                                               int* __restrict__ bcur,
                                               unsigned int* __restrict__ tmp, int E) {
    __shared__ int lcnt[NBUCK];
    __shared__ int lbase[NBUCK];
    for (int i = threadIdx.x; i < NBUCK; i += 256) lcnt[i] = 0;
    __syncthreads();

    int4 sreg[EPT / 4], dreg[EPT / 4];
    int base4 = blockIdx.x * (TILE / 4);
#pragma unroll
    for (int j = 0; j < EPT / 4; ++j) {
        int i4 = base4 + j * 256 + threadIdx.x;
        if (i4 < E / 4) {
            sreg[j] = ((const int4*)src)[i4];
            dreg[j] = ((const int4*)dst)[i4];
            atomicAdd(&lcnt[dreg[j].x >> BSH], 1);
            atomicAdd(&lcnt[dreg[j].y >> BSH], 1);
            atomicAdd(&lcnt[dreg[j].z >> BSH], 1);
            atomicAdd(&lcnt[dreg[j].w >> BSH], 1);
        } else {
            dreg[j].x = -1;
        }
    }
    __syncthreads();
    for (int b = threadIdx.x; b < NBUCK; b += 256) {
        int c = lcnt[b];
        lbase[b] = c ? atomicAdd(&bcur[b], c) : 0;
        lcnt[b] = 0;
    }
    __syncthreads();
#pragma unroll
    for (int j = 0; j < EPT / 4; ++j) {
        if (dreg[j].x >= 0) {
            int d, s, b, r;
            d = dreg[j].x; s = sreg[j].x; b = d >> BSH;
            r = atomicAdd(&lcnt[b], 1);
            tmp[lbase[b] + r] = (unsigned int)s | ((unsigned int)(d & 255) << 17);
            d = dreg[j].y; s = sreg[j].y; b = d >> BSH;
            r = atomicAdd(&lcnt[b], 1);
            tmp[lbase[b] + r] = (unsigned int)s | ((unsigned int)(d & 255) << 17);
            d = dreg[j].z; s = sreg[j].z; b = d >> BSH;
            r = atomicAdd(&lcnt[b], 1);
            tmp[lbase[b] + r] = (unsigned int)s | ((unsigned int)(d & 255) << 17);
            d = dreg[j].w; s = sreg[j].w; b = d >> BSH;
            r = atomicAdd(&lcnt[b], 1);
            tmp[lbase[b] + r] = (unsigned int)s | ((unsigned int)(d & 255) << 17);
        }
    }
}

// ---------------- passB: per-bucket node sort (in-place), rowinfo, inv ----------------
__global__ __launch_bounds__(256) void passB_k(unsigned int* __restrict__ tmp,  // in: bucketed; out: esrc (in place)
                                               const int* __restrict__ bcur,
                                               unsigned int* __restrict__ rowinfo,
                                               float* __restrict__ inv) {
    __shared__ unsigned int buf[CAP];
    __shared__ int cnt[256];
    __shared__ int cur[256];
    __shared__ int ls[256];
    int b = blockIdx.x;
    int beg0 = b * CAP;
    int cntb = bcur[b] - beg0;

    cnt[threadIdx.x] = 0;
    __syncthreads();
    for (int i = threadIdx.x; i < cntb; i += 256) {
        unsigned int v = tmp[beg0 + i];
        buf[i] = v;
        atomicAdd(&cnt[v >> 17], 1);
    }
    __syncthreads();

    int a = cnt[threadIdx.x];
    ls[threadIdx.x] = a;
    __syncthreads();
    for (int off = 1; off < 256; off <<= 1) {
        int p = (threadIdx.x >= off) ? ls[threadIdx.x - off] : 0;
        __syncthreads();
        ls[threadIdx.x] += p;
        __syncthreads();
    }
    int excl = ls[threadIdx.x] - a;
    int p0 = beg0 + excl;
    cur[threadIdx.x] = p0;
    int n = (b << BSH) + threadIdx.x;
    if (n < N_NODES) {
        rowinfo[n] = (unsigned int)p0 | ((unsigned int)a << 22);
        inv[n] = rsqrtf((float)(a + 1));
    }
    __syncthreads();

    for (int i = threadIdx.x; i < cntb; i += 256) {
        unsigned int v = buf[i];
        int pos = atomicAdd(&cur[v >> 17], 1);
        tmp[pos] = v & 0x1FFFFu;
    }
}

// ---------------- linear: h_pre = (x*W + b) * inv[n], fp16, feature-chunked ----------------
__global__ __launch_bounds__(256) void linear_k(const float* __restrict__ x,
                                                const float* __restrict__ W,
                                                const float* __restrict__ bias,
                                                const float* __restrict__ inv,
                                                __half* __restrict__ h, int N) {
    __shared__ float Ws[F_DIM][F_DIM];
    __shared__ float bs[F_DIM];
    for (int i = threadIdx.x; i < F_DIM * F_DIM; i += 256) Ws[i >> 6][i & 63] = W[i];
    if (threadIdx.x < F_DIM) bs[threadIdx.x] = bias[threadIdx.x];
    __syncthreads();

    int n = blockIdx.x * 256 + threadIdx.x;
    if (n >= N) return;

    float xr[F_DIM];
    const float4* xp = (const float4*)(x + (size_t)n * F_DIM);
#pragma unroll
    for (int k4 = 0; k4 < 16; ++k4) {
        float4 v = xp[k4];
        xr[k4 * 4 + 0] = v.x; xr[k4 * 4 + 1] = v.y;
        xr[k4 * 4 + 2] = v.z; xr[k4 * 4 + 3] = v.w;
    }
    float invn = inv[n];
#pragma unroll 1
    for (int f0 = 0; f0 < F_DIM; f0 += 4) {
        float a0 = bs[f0 + 0], a1 = bs[f0 + 1], a2 = bs[f0 + 2], a3 = bs[f0 + 3];
#pragma unroll
        for (int k = 0; k < F_DIM; ++k) {
            float xv = xr[k];
            a0 += xv * Ws[k][f0 + 0];
            a1 += xv * Ws[k][f0 + 1];
            a2 += xv * Ws[k][f0 + 2];
            a3 += xv * Ws[k][f0 + 3];
        }
        union { __half2 h2[2]; float2 f2; } u;
        u.h2[0] = __floats2half2_rn(a0 * invn, a1 * invn);
        u.h2[1] = __floats2half2_rn(a2 * invn, a3 * invn);
        // chunk c = f0>>4 ; within-chunk offset f0&15
        *((float2*)(h + ((size_t)(f0 >> 4) * N + n) * 16 + (f0 & 15))) = u.f2;
    }
}

// ---------------- gelu (tanh approximation, jax.nn.gelu default) ----------------
__device__ __forceinline__ float gelu1(float x) {
    float x3 = x * x * x;
    float t = tanhf(0.7978845608028654f * (x + 0.044715f * x3));
    return 0.5f * x * (1.0f + t);
}

// ---------------- gather (per feature-chunk): wave per node, 8 edge-slots x 8 fpairs ----------------
__global__ __launch_bounds__(256) void gather_k(const __half* __restrict__ hc,   // chunk base: [N][16] halves
                                                const float* __restrict__ inv,
                                                const unsigned int* __restrict__ rowinfo,
                                                const unsigned int* __restrict__ esrc,
                                                float* __restrict__ outc, int N) {
    int n = blockIdx.x * 4 + (threadIdx.x >> 6);
    if (n >= N) return;
    int lane = threadIdx.x & 63;
    int fp = lane & 7;          // feature pair (features 2fp, 2fp+1 of this chunk)
    int eslot = lane >> 3;      // 8 edges in flight per wave

    unsigned int ri = rowinfo[n];
    int beg = ri & 0x3FFFFF;
    int deg = ri >> 22;

    float ax = 0.f, ay = 0.f;
    for (int k = eslot; k < deg; k += 8) {
        int s = (int)esrc[beg + k];
        __half2 v = *((const __half2*)(hc + (size_t)s * 16) + fp);
        float2 f = __half22float2(v);
        ax += f.x; ay += f.y;          // h_pre already includes inv[s]
    }
    ax += __shfl_xor(ax, 8);  ay += __shfl_xor(ay, 8);
    ax += __shfl_xor(ax, 16); ay += __shfl_xor(ay, 16);
    ax += __shfl_xor(ax, 32); ay += __shfl_xor(ay, 32);

    if (eslot == 0) {
        float invn = inv[n];
        __half2 sv = *((const __half2*)(hc + (size_t)n * 16) + fp);
        float2 sf = __half22float2(sv);
        // self: h_pre[n] = h[n]*invn; final *invn gives h[n]*invn^2 — no extra factor
        float rx = (ax + sf.x) * invn;
        float ry = (ay + sf.y) * invn;
        float2 o;
        o.x = gelu1(rx);
        o.y = gelu1(ry);
        ((float2*)(outc + (size_t)n * F_DIM))[fp] = o;
    }
}

extern "C" void kernel_launch(void* const* d_in, const int* in_sizes, int n_in,
                              void* d_out, int out_size, void* d_ws, size_t ws_size,
                              hipStream_t stream) {
    const float* x    = (const float*)d_in[0];
    const int*   ei   = (const int*)d_in[1];
    const float* W    = (const float*)d_in[2];
    const float* bias = (const float*)d_in[3];
    float* out = (float*)d_out;

    const int* src = ei;             // edge_index[0]
    const int* dst = ei + N_EDGES;   // edge_index[1]

    // workspace (~26.5 MB)
    unsigned int* tmp     = (unsigned int*)d_ws;              // NBUCK*CAP uints = 12.8 MB (doubles as esrc, in-place)
    unsigned int* rowinfo = tmp + (size_t)NBUCK * CAP;        // N uints
    float*        inv     = (float*)(rowinfo + N_NODES);      // N floats
    int*          bcur    = (int*)(inv + N_NODES);            // NBUCK ints
    size_t off = (size_t)(bcur + NBUCK) - (size_t)d_ws;
    off = (off + 31) & ~(size_t)31;
    __half* h = (__half*)((char*)d_ws + off);                 // 4 chunks x N x 16 halves = 12.8 MB

    init_k<<<(NBUCK + 255) / 256, 256, 0, stream>>>(bcur);
    pass1_k<<<(N_EDGES + TILE - 1) / TILE, 256, 0, stream>>>(src, dst, bcur, tmp, N_EDGES);
    passB_k<<<NBUCK, 256, 0, stream>>>(tmp, bcur, rowinfo, inv);
    linear_k<<<(N_NODES + 255) / 256, 256, 0, stream>>>(x, W, bias, inv, h, N_NODES);
#pragma unroll
    for (int c = 0; c < 4; ++c) {
        gather_k<<<(N_NODES + 3) / 4, 256, 0, stream>>>(h + (size_t)c * N_NODES * 16, inv,
                                                        rowinfo, tmp, out + c * 16, N_NODES);
    }
}

// Round 7
// 126.363 us; speedup vs baseline: 1.6878x; 1.6878x over previous
//
#include <hip/hip_runtime.h>
#include <hip/hip_fp16.h>
#include <math.h>

#define N_NODES 100000
#define N_EDGES 1600000
#define F_DIM 64
#define BSH 8                              // 256 nodes per bucket
#define NBUCK ((N_NODES + 255) >> 8)       // 391
#define CAP 8192                           // slots/bucket (avg 4092, ~64 sigma headroom)
#define EPT 16
#define TILE (256 * EPT)                   // 4096 edges per pass1 block

// ---------------- init bucket cursors ----------------
__global__ __launch_bounds__(256) void init_k(int* __restrict__ bcur) {
    int i = blockIdx.x * 256 + threadIdx.x;
    if (i < NBUCK) bcur[i] = i * CAP;
}

// ---------------- pass1: single-pass bucket scatter (fixed-capacity) ----------------
__global__ __launch_bounds__(256) void pass1_k(const int* __restrict__ src,
                                               const int* __restrict__ dst,
                                               int* __restrict__ bcur,
                                               unsigned int* __restrict__ tmp, int E) {
    __shared__ int lcnt[NBUCK];
    __shared__ int lbase[NBUCK];
    for (int i = threadIdx.x; i < NBUCK; i += 256) lcnt[i] = 0;
    __syncthreads();

    int4 sreg[EPT / 4], dreg[EPT / 4];
    int base4 = blockIdx.x * (TILE / 4);
#pragma unroll
    for (int j = 0; j < EPT / 4; ++j) {
        int i4 = base4 + j * 256 + threadIdx.x;
        if (i4 < E / 4) {
            sreg[j] = ((const int4*)src)[i4];
            dreg[j] = ((const int4*)dst)[i4];
            atomicAdd(&lcnt[dreg[j].x >> BSH], 1);
            atomicAdd(&lcnt[dreg[j].y >> BSH], 1);
            atomicAdd(&lcnt[dreg[j].z >> BSH], 1);
            atomicAdd(&lcnt[dreg[j].w >> BSH], 1);
        } else {
            dreg[j].x = -1;
        }
    }
    __syncthreads();
    for (int b = threadIdx.x; b < NBUCK; b += 256) {
        int c = lcnt[b];
        lbase[b] = c ? atomicAdd(&bcur[b], c) : 0;
        lcnt[b] = 0;
    }
    __syncthreads();
#pragma unroll
    for (int j = 0; j < EPT / 4; ++j) {
        if (dreg[j].x >= 0) {
            int d, s, b, r;
            d = dreg[j].x; s = sreg[j].x; b = d >> BSH;
            r = atomicAdd(&lcnt[b], 1);
            tmp[lbase[b] + r] = (unsigned int)s | ((unsigned int)(d & 255) << 17);
            d = dreg[j].y; s = sreg[j].y; b = d >> BSH;
            r = atomicAdd(&lcnt[b], 1);
            tmp[lbase[b] + r] = (unsigned int)s | ((unsigned int)(d & 255) << 17);
            d = dreg[j].z; s = sreg[j].z; b = d >> BSH;
            r = atomicAdd(&lcnt[b], 1);
            tmp[lbase[b] + r] = (unsigned int)s | ((unsigned int)(d & 255) << 17);
            d = dreg[j].w; s = sreg[j].w; b = d >> BSH;
            r = atomicAdd(&lcnt[b], 1);
            tmp[lbase[b] + r] = (unsigned int)s | ((unsigned int)(d & 255) << 17);
        }
    }
}

// ---------------- passB: per-bucket node sort (in-place), rowinfo, inv ----------------
__global__ __launch_bounds__(256) void passB_k(unsigned int* __restrict__ tmp,  // in: bucketed; out: esrc (in place)
                                               const int* __restrict__ bcur,
                                               unsigned int* __restrict__ rowinfo,
                                               float* __restrict__ inv) {
    __shared__ unsigned int buf[CAP];
    __shared__ int cnt[256];
    __shared__ int cur[256];
    __shared__ int ls[256];
    int b = blockIdx.x;
    int beg0 = b * CAP;
    int cntb = bcur[b] - beg0;

    cnt[threadIdx.x] = 0;
    __syncthreads();
    for (int i = threadIdx.x; i < cntb; i += 256) {
        unsigned int v = tmp[beg0 + i];
        buf[i] = v;
        atomicAdd(&cnt[v >> 17], 1);
    }
    __syncthreads();

    int a = cnt[threadIdx.x];
    ls[threadIdx.x] = a;
    __syncthreads();
    for (int off = 1; off < 256; off <<= 1) {
        int p = (threadIdx.x >= off) ? ls[threadIdx.x - off] : 0;
        __syncthreads();
        ls[threadIdx.x] += p;
        __syncthreads();
    }
    int excl = ls[threadIdx.x] - a;
    int p0 = beg0 + excl;
    cur[threadIdx.x] = p0;
    int n = (b << BSH) + threadIdx.x;
    if (n < N_NODES) {
        rowinfo[n] = (unsigned int)p0 | ((unsigned int)a << 22);
        inv[n] = rsqrtf((float)(a + 1));
    }
    __syncthreads();

    for (int i = threadIdx.x; i < cntb; i += 256) {
        unsigned int v = buf[i];
        int pos = atomicAdd(&cur[v >> 17], 1);
        tmp[pos] = v & 0x1FFFFu;
    }
}

// ---------------- linear: h_pre = (x*W + b) * inv[n], fp16 [N][64] ----------------
__global__ __launch_bounds__(256) void linear_k(const float* __restrict__ x,
                                                const float* __restrict__ W,
                                                const float* __restrict__ bias,
                                                const float* __restrict__ inv,
                                                __half* __restrict__ h, int N) {
    __shared__ float Ws[F_DIM][F_DIM];
    __shared__ float bs[F_DIM];
    for (int i = threadIdx.x; i < F_DIM * F_DIM; i += 256) Ws[i >> 6][i & 63] = W[i];
    if (threadIdx.x < F_DIM) bs[threadIdx.x] = bias[threadIdx.x];
    __syncthreads();

    int n = blockIdx.x * 256 + threadIdx.x;
    if (n >= N) return;

    float xr[F_DIM];
    const float4* xp = (const float4*)(x + (size_t)n * F_DIM);
#pragma unroll
    for (int k4 = 0; k4 < 16; ++k4) {
        float4 v = xp[k4];
        xr[k4 * 4 + 0] = v.x; xr[k4 * 4 + 1] = v.y;
        xr[k4 * 4 + 2] = v.z; xr[k4 * 4 + 3] = v.w;
    }
    float invn = inv[n];
    __half* hp = h + (size_t)n * F_DIM;
#pragma unroll 1
    for (int f0 = 0; f0 < F_DIM; f0 += 4) {
        float a0 = bs[f0 + 0], a1 = bs[f0 + 1], a2 = bs[f0 + 2], a3 = bs[f0 + 3];
#pragma unroll
        for (int k = 0; k < F_DIM; ++k) {
            float xv = xr[k];
            a0 += xv * Ws[k][f0 + 0];
            a1 += xv * Ws[k][f0 + 1];
            a2 += xv * Ws[k][f0 + 2];
            a3 += xv * Ws[k][f0 + 3];
        }
        union { __half2 h2[2]; float2 f2; } u;
        u.h2[0] = __floats2half2_rn(a0 * invn, a1 * invn);
        u.h2[1] = __floats2half2_rn(a2 * invn, a3 * invn);
        *((float2*)(hp + f0)) = u.f2;
    }
}

// ---------------- gelu (tanh approximation, jax.nn.gelu default) ----------------
__device__ __forceinline__ float gelu1(float x) {
    float x3 = x * x * x;
    float t = tanhf(0.7978845608028654f * (x + 0.044715f * x3));
    return 0.5f * x * (1.0f + t);
}

// ---------------- gather: wave per node; half-wave per edge; half2 per lane; 8 edges in flight ----------------
__global__ __launch_bounds__(256) void gather_k(const __half* __restrict__ h,    // h_pre [N][64]
                                                const float* __restrict__ inv,
                                                const unsigned int* __restrict__ rowinfo,
                                                const unsigned int* __restrict__ esrc,
                                                float* __restrict__ out, int N) {
    int n = blockIdx.x * 4 + (threadIdx.x >> 6);
    if (n >= N) return;
    int lane = threadIdx.x & 63;
    int half_id = lane >> 5;    // 0: even edge slots, 1: odd
    int fl = lane & 31;         // feature pair (features 2fl, 2fl+1)

    unsigned int ri = rowinfo[n];
    int beg = (int)(ri & 0x3FFFFFu);
    int deg = (int)(ri >> 22);

    float ax = 0.f, ay = 0.f;
    int k = half_id;
    // unroll 4: eight edges in flight per wave
    for (; k + 6 < deg; k += 8) {
        int s0 = (int)esrc[beg + k];
        int s1 = (int)esrc[beg + k + 2];
        int s2 = (int)esrc[beg + k + 4];
        int s3 = (int)esrc[beg + k + 6];
        __half2 v0 = *((const __half2*)(h + (size_t)s0 * F_DIM) + fl);
        __half2 v1 = *((const __half2*)(h + (size_t)s1 * F_DIM) + fl);
        __half2 v2 = *((const __half2*)(h + (size_t)s2 * F_DIM) + fl);
        __half2 v3 = *((const __half2*)(h + (size_t)s3 * F_DIM) + fl);
        float2 f0 = __half22float2(v0);
        float2 f1 = __half22float2(v1);
        float2 f2 = __half22float2(v2);
        float2 f3 = __half22float2(v3);
        ax += (f0.x + f1.x) + (f2.x + f3.x);
        ay += (f0.y + f1.y) + (f2.y + f3.y);
    }
    for (; k < deg; k += 2) {
        int s0 = (int)esrc[beg + k];
        __half2 v0 = *((const __half2*)(h + (size_t)s0 * F_DIM) + fl);
        float2 f0 = __half22float2(v0);
        ax += f0.x; ay += f0.y;
    }
    // merge even/odd halves
    ax += __shfl_xor(ax, 32);
    ay += __shfl_xor(ay, 32);

    if (half_id == 0) {
        float invn = inv[n];
        __half2 sv = *((const __half2*)(h + (size_t)n * F_DIM) + fl);
        float2 sf = __half22float2(sv);
        // self: h_pre[n] = h[n]*invn; final *invn gives h[n]*invn^2
        float rx = (ax + sf.x) * invn;
        float ry = (ay + sf.y) * invn;
        float2 o;
        o.x = gelu1(rx);
        o.y = gelu1(ry);
        ((float2*)(out + (size_t)n * F_DIM))[fl] = o;
    }
}

extern "C" void kernel_launch(void* const* d_in, const int* in_sizes, int n_in,
                              void* d_out, int out_size, void* d_ws, size_t ws_size,
                              hipStream_t stream) {
    const float* x    = (const float*)d_in[0];
    const int*   ei   = (const int*)d_in[1];
    const float* W    = (const float*)d_in[2];
    const float* bias = (const float*)d_in[3];
    float* out = (float*)d_out;

    const int* src = ei;             // edge_index[0]
    const int* dst = ei + N_EDGES;   // edge_index[1]

    // workspace (~26.5 MB)
    unsigned int* tmp     = (unsigned int*)d_ws;              // NBUCK*CAP uints = 12.8 MB (doubles as esrc, in-place)
    unsigned int* rowinfo = tmp + (size_t)NBUCK * CAP;        // N uints
    float*        inv     = (float*)(rowinfo + N_NODES);      // N floats
    int*          bcur    = (int*)(inv + N_NODES);            // NBUCK ints
    size_t off = (size_t)(bcur + NBUCK) - (size_t)d_ws;
    off = (off + 31) & ~(size_t)31;
    __half* h = (__half*)((char*)d_ws + off);                 // N*64 halves = 12.8 MB

    init_k<<<(NBUCK + 255) / 256, 256, 0, stream>>>(bcur);
    pass1_k<<<(N_EDGES + TILE - 1) / TILE, 256, 0, stream>>>(src, dst, bcur, tmp, N_EDGES);
    passB_k<<<NBUCK, 256, 0, stream>>>(tmp, bcur, rowinfo, inv);
    linear_k<<<(N_NODES + 255) / 256, 256, 0, stream>>>(x, W, bias, inv, h, N_NODES);
    gather_k<<<(N_NODES + 3) / 4, 256, 0, stream>>>(h, inv, rowinfo, tmp, out, N_NODES);
}